// Round 2
// baseline (564.280 us; speedup 1.0000x reference)
//
#include <hip/hip_runtime.h>
#include <hip/hip_bf16.h>
#include <cstdint>
#include <cstddef>

// Problem constants (fixed by the reference).
#define T_STEPS 128
#define BATCH   256
#define IN_F    1024
#define H1_F    2048
#define H2_F    2048
#define OUT_F   512
#define M_TOT   (T_STEPS * BATCH)   // 32768

typedef __attribute__((ext_vector_type(8))) short bf16x8;   // 8 bf16 = 4 VGPRs
typedef __attribute__((ext_vector_type(4))) float f32x4;

__device__ __forceinline__ void load16_to_lds(const void* g, void* l) {
  __builtin_amdgcn_global_load_lds(
      (const __attribute__((address_space(1))) void*)g,
      (__attribute__((address_space(3))) void*)l, 16, 0, 0);
}

__device__ __forceinline__ unsigned short f2bf(float x) {
  __hip_bfloat16 h = __float2bfloat16(x);
  return *reinterpret_cast<unsigned short*>(&h);
}

// ---------------------------------------------------------------------------
// fp32 -> bf16 conversion, 4 elems/thread (float4 in, ushort4 out). n4 = n/4.
// ---------------------------------------------------------------------------
__global__ __launch_bounds__(256) void cvt_f32_bf16(
    const float4* __restrict__ in, ushort4* __restrict__ out, int n4) {
  int i = threadIdx.x + blockIdx.x * 256;
  if (i < n4) {
    float4 v = in[i];
    ushort4 o;
    o.x = f2bf(v.x); o.y = f2bf(v.y); o.z = f2bf(v.z); o.w = f2bf(v.w);
    out[i] = o;
  }
}

// ---------------------------------------------------------------------------
// C[M_TOT x N] = A[M_TOT x K] * B[N x K]^T   (bf16 in, bf16 out, K=IN_F)
// m97-style: 128x128 tile, BK=64, 4 waves each owning a 64x64 quadrant,
// global_load_lds width=16, XOR-swizzled LDS cells for conflict-free b128 reads.
// ---------------------------------------------------------------------------
__global__ __launch_bounds__(256) void gemm_bt(
    const __hip_bfloat16* __restrict__ A, const __hip_bfloat16* __restrict__ B,
    __hip_bfloat16* __restrict__ C, int N) {
  __shared__ uint4 lA[1024];  // 128 rows x 8 cells x 16B = 16 KB
  __shared__ uint4 lB[1024];
  const int K = IN_F;
  const int tid = threadIdx.x, lane = tid & 63, wv = tid >> 6;
  const int wm = (wv & 1) * 64, wn = (wv >> 1) * 64;
  const int m0 = blockIdx.x * 128, n0 = blockIdx.y * 128;
  const int mk = lane & 15, grp = lane >> 4;

  f32x4 acc[4][4] = {};

  for (int kt = 0; kt < K; kt += 64) {
#pragma unroll
    for (int i = 0; i < 4; ++i) {
      int cellbase = (wv * 4 + i) * 64;      // wave-uniform LDS base
      int cell = cellbase + lane;
      int r  = cell >> 3;                    // tile row 0..127
      int kb = (cell & 7) ^ (r & 7);         // swizzled k-block
      load16_to_lds(A + (size_t)(m0 + r) * K + kt + kb * 8, &lA[cellbase]);
      load16_to_lds(B + (size_t)(n0 + r) * K + kt + kb * 8, &lB[cellbase]);
    }
    __syncthreads();
#pragma unroll
    for (int ks = 0; ks < 2; ++ks) {
      bf16x8 af[4], bfr[4];
      const int kb = ks * 4 + grp;
#pragma unroll
      for (int f = 0; f < 4; ++f) {
        int m = wm + f * 16 + mk;
        af[f]  = *(const bf16x8*)&lA[m * 8 + (kb ^ (m & 7))];
        int n = wn + f * 16 + mk;
        bfr[f] = *(const bf16x8*)&lB[n * 8 + (kb ^ (n & 7))];
      }
#pragma unroll
      for (int i = 0; i < 4; ++i)
#pragma unroll
        for (int j = 0; j < 4; ++j)
          acc[i][j] = __builtin_amdgcn_mfma_f32_16x16x32_bf16(af[i], bfr[j], acc[i][j], 0, 0, 0);
    }
    __syncthreads();
  }

  // Epilogue. C/D mapping (m89-verified): col = lane&15, row = (lane>>4)*4 + reg.
#pragma unroll
  for (int i = 0; i < 4; ++i)
#pragma unroll
    for (int j = 0; j < 4; ++j) {
      int row = m0 + wm + i * 16 + grp * 4;
      int col = n0 + wn + j * 16 + mk;
#pragma unroll
      for (int r = 0; r < 4; ++r)
        C[(size_t)(row + r) * N + col] = __float2bfloat16(acc[i][j][r]);
    }
}

// ---------------------------------------------------------------------------
// Per-neuron LIF scan for layer 1 over one H1 chunk. Thread = (b, h).
// Reads cur1 chunk (bf16), emits spike bitmask via 64-lane ballot.
// ---------------------------------------------------------------------------
__global__ __launch_bounds__(256) void scan1_kernel(
    const __hip_bfloat16* __restrict__ cur1, const float* __restrict__ b1,
    const float* __restrict__ wt1, unsigned long long* __restrict__ mask1,
    int h_off, int Nc) {
  const int hl = threadIdx.x + blockIdx.x * 256;     // within chunk
  const int b  = blockIdx.y;
  const int hg = h_off + hl;                         // global h1
  const int lane = threadIdx.x & 63;
  const float bias = b1[hg];
  const float w    = wt1[hg];
  const float tau  = 0.1f + 1.0f / (1.0f + expf(-w));
  const float k    = 0.01f / tau;
  float v = 0.0f;
  for (int t = 0; t < T_STEPS; ++t) {
    float cur = __bfloat162float(cur1[(size_t)(t * BATCH + b) * Nc + hl]) + bias;
    v = fmaf(k, cur - v, v);
    bool sp = (v - 1.0f) > 0.0f;
    unsigned long long bm = __ballot(sp);
    if (lane == 0) mask1[(size_t)(t * BATCH + b) * (H1_F / 64) + (hg >> 6)] = bm;
    if (sp) v = 0.0f;
  }
}

// ---------------------------------------------------------------------------
// Event-driven current: cur = bias + sum over set bits i of Wrow[i].
// mask row = 32 u64 words per (t,b); lanes<32 hold them, ballot fast-path.
// Exact for any input; ~zero work when no spikes.
// ---------------------------------------------------------------------------
__device__ __forceinline__ float event_current(
    const unsigned long long* __restrict__ mrow, const float* __restrict__ Wrow,
    int lane, float bias) {
  unsigned long long wrd = (lane < 32) ? mrow[lane] : 0ull;
  float cur = bias;
  if (__ballot(wrd != 0ull)) {
    for (int wi = 0; wi < 32; ++wi) {
      unsigned long long m = __shfl(wrd, wi, 64);
      while (m) {
        int bit = __ffsll(m) - 1;
        m &= m - 1;
        cur += Wrow[wi * 64 + bit];
      }
    }
  }
  return cur;
}

__global__ __launch_bounds__(256) void layer2_kernel(
    const unsigned long long* __restrict__ mask1, const float* __restrict__ W2,
    const float* __restrict__ b2, const float* __restrict__ wt2,
    unsigned long long* __restrict__ mask2) {
  const int h2 = threadIdx.x + blockIdx.x * 256;
  const int b  = blockIdx.y;
  const int lane = threadIdx.x & 63;
  const float bias = b2[h2];
  const float w    = wt2[h2];
  const float tau  = 0.1f + 1.0f / (1.0f + expf(-w));
  const float k    = 0.01f / tau;
  const float* Wrow = W2 + (size_t)h2 * H1_F;
  float v = 0.0f;
  for (int t = 0; t < T_STEPS; ++t) {
    float cur = event_current(mask1 + (size_t)(t * BATCH + b) * 32, Wrow, lane, bias);
    v = fmaf(k, cur - v, v);
    bool sp = (v - 1.0f) > 0.0f;
    unsigned long long bm = __ballot(sp);
    if (lane == 0) mask2[(size_t)(t * BATCH + b) * (H2_F / 64) + (h2 >> 6)] = bm;
    if (sp) v = 0.0f;
  }
}

__global__ __launch_bounds__(256) void layer3_kernel(
    const unsigned long long* __restrict__ mask2, const float* __restrict__ W3,
    const float* __restrict__ b3, const float* __restrict__ wt3,
    float* __restrict__ out_s, float* __restrict__ out_v) {
  const int o = threadIdx.x + blockIdx.x * 256;
  const int b = blockIdx.y;
  const int lane = threadIdx.x & 63;
  const float bias = b3[o];
  const float w    = wt3[o];
  const float tau  = 0.1f + 1.0f / (1.0f + expf(-w));
  const float k    = 0.01f / tau;
  const float* Wrow = W3 + (size_t)o * H2_F;
  float v = 0.0f;
  for (int t = 0; t < T_STEPS; ++t) {
    float cur = event_current(mask2 + (size_t)(t * BATCH + b) * 32, Wrow, lane, bias);
    float vp = fmaf(k, cur - v, v);          // pre-reset membrane (v_tmp)
    bool sp = (vp - 1.0f) > 0.0f;
    size_t idx = (size_t)(t * BATCH + b) * OUT_F + o;
    out_s[idx] = sp ? 1.0f : 0.0f;
    out_v[idx] = vp;
    v = sp ? 0.0f : vp;
  }
}

// ---------------------------------------------------------------------------
extern "C" void kernel_launch(void* const* d_in, const int* in_sizes, int n_in,
                              void* d_out, int out_size, void* d_ws, size_t ws_size,
                              hipStream_t stream) {
  const float* s   = (const float*)d_in[0];
  const float* W1  = (const float*)d_in[1];
  const float* b1  = (const float*)d_in[2];
  const float* wt1 = (const float*)d_in[3];
  const float* W2  = (const float*)d_in[4];
  const float* b2  = (const float*)d_in[5];
  const float* wt2 = (const float*)d_in[6];
  const float* W3  = (const float*)d_in[7];
  const float* b3  = (const float*)d_in[8];
  const float* wt3 = (const float*)d_in[9];

  // Workspace layout: [mask1 8MB][mask2 8MB][s_bf16 67MB][W1_bf16 4MB][cur1 chunk]
  char* wsb = (char*)d_ws;
  const size_t MASK_BYTES = (size_t)T_STEPS * BATCH * (H1_F / 64) * 8;  // 8.4 MB
  const size_t S_ELEMS  = (size_t)M_TOT * IN_F;     // 33.55M
  const size_t W1_ELEMS = (size_t)H1_F * IN_F;      // 2.10M
  unsigned long long* mask1 = (unsigned long long*)wsb;
  unsigned long long* mask2 = (unsigned long long*)(wsb + MASK_BYTES);
  __hip_bfloat16* s_bf  = (__hip_bfloat16*)(wsb + 2 * MASK_BYTES);
  __hip_bfloat16* W1_bf = s_bf + S_ELEMS;
  __hip_bfloat16* cur1  = W1_bf + W1_ELEMS;
  const size_t fixed = 2 * MASK_BYTES + (S_ELEMS + W1_ELEMS) * sizeof(__hip_bfloat16);

  // Adaptive H1 chunking: fewest chunks whose cur1 buffer fits remaining ws.
  const size_t avail = ws_size > fixed ? ws_size - fixed : 0;
  int nc = 8;
  for (int c = 1; c <= 8; c *= 2) {
    if ((size_t)M_TOT * (H1_F / c) * sizeof(__hip_bfloat16) <= avail) { nc = c; break; }
  }
  const int Nc = H1_F / nc;   // >= 256

  float* outs = (float*)d_out;
  float* outv = outs + (size_t)T_STEPS * BATCH * OUT_F;

  // fp32 -> bf16 conversions (s is exactly representable: values in {0,1})
  cvt_f32_bf16<<<(S_ELEMS / 4 + 255) / 256, 256, 0, stream>>>(
      (const float4*)s, (ushort4*)s_bf, (int)(S_ELEMS / 4));
  cvt_f32_bf16<<<(W1_ELEMS / 4 + 255) / 256, 256, 0, stream>>>(
      (const float4*)W1, (ushort4*)W1_bf, (int)(W1_ELEMS / 4));

  for (int c = 0; c < nc; ++c) {
    gemm_bt<<<dim3(M_TOT / 128, Nc / 128), 256, 0, stream>>>(
        s_bf, W1_bf + (size_t)c * Nc * IN_F, cur1, Nc);
    scan1_kernel<<<dim3(Nc / 256, BATCH), 256, 0, stream>>>(
        cur1, b1, wt1, mask1, c * Nc, Nc);
  }
  layer2_kernel<<<dim3(H2_F / 256, BATCH), 256, 0, stream>>>(mask1, W2, b2, wt2, mask2);
  layer3_kernel<<<dim3(OUT_F / 256, BATCH), 256, 0, stream>>>(mask2, W3, b3, wt3, outs, outv);
}

// Round 3
// 514.465 us; speedup vs baseline: 1.0968x; 1.0968x over previous
//
#include <hip/hip_runtime.h>
#include <hip/hip_bf16.h>
#include <cstdint>
#include <cstddef>

// Problem constants (fixed by the reference).
#define T_STEPS 128
#define BATCH   256
#define IN_F    1024
#define H1_F    2048
#define H2_F    2048
#define OUT_F   512
#define M_TOT   (T_STEPS * BATCH)   // 32768

typedef __attribute__((ext_vector_type(8))) short bf16x8;   // 8 bf16 = 4 VGPRs
typedef __attribute__((ext_vector_type(4))) float f32x4;

__device__ __forceinline__ void load16_to_lds(const void* g, void* l) {
  __builtin_amdgcn_global_load_lds(
      (const __attribute__((address_space(1))) void*)g,
      (__attribute__((address_space(3))) void*)l, 16, 0, 0);
}

__device__ __forceinline__ unsigned short f2bf(float x) {
  __hip_bfloat16 h = __float2bfloat16(x);
  return *reinterpret_cast<unsigned short*>(&h);
}

__device__ __forceinline__ float lif_k(float w) {
  float tau = 0.1f + 1.0f / (1.0f + expf(-w));
  return 0.01f / tau;
}

// ---------------------------------------------------------------------------
// Fused fp32 -> bf16 conversion of s (exact: values {0,1}) and W1.
// 4 elems/thread. One launch instead of two.
// ---------------------------------------------------------------------------
__global__ __launch_bounds__(256) void cvt_both(
    const float4* __restrict__ s_in, ushort4* __restrict__ s_out, int s4,
    const float4* __restrict__ w_in, ushort4* __restrict__ w_out, int w4) {
  int i = threadIdx.x + blockIdx.x * 256;
  const float4* in;
  ushort4* out;
  if (i < s4) {
    in = s_in + i; out = s_out + i;
  } else {
    int j = i - s4;
    if (j >= w4) return;
    in = w_in + j; out = w_out + j;
  }
  float4 v = *in;
  ushort4 o;
  o.x = f2bf(v.x); o.y = f2bf(v.y); o.z = f2bf(v.z); o.w = f2bf(v.w);
  *out = o;
}

// ---------------------------------------------------------------------------
// C[M_TOT x N] = A[M_TOT x K] * B[N x K]^T   (bf16 in/out, K=IN_F)
// m97-style: 128x128 tile, BK=64, 4 waves each owning a 64x64 quadrant,
// global_load_lds width=16, XOR-swizzled LDS cells, supertile block remap
// (4 m-tiles x all n-tiles) for per-XCD L2 reuse of A.
// ---------------------------------------------------------------------------
__global__ __launch_bounds__(256) void gemm_bt(
    const __hip_bfloat16* __restrict__ A, const __hip_bfloat16* __restrict__ B,
    __hip_bfloat16* __restrict__ C, int N) {
  __shared__ uint4 lA[1024];  // 128 rows x 8 cells x 16B = 16 KB
  __shared__ uint4 lB[1024];
  const int K = IN_F;
  const int tid = threadIdx.x, lane = tid & 63, wv = tid >> 6;
  const int wm = (wv & 1) * 64, wn = (wv >> 1) * 64;

  // supertile remap: consecutive blocks = 4 m-tiles x ntiles n-tiles
  const int ntiles = N >> 7;
  const int id = blockIdx.x;
  const int group = id / (4 * ntiles);
  const int within = id % (4 * ntiles);
  const int m0 = (group * 4 + within / ntiles) * 128;
  const int n0 = (within % ntiles) * 128;

  const int mk = lane & 15, grp = lane >> 4;

  f32x4 acc[4][4] = {};

  for (int kt = 0; kt < K; kt += 64) {
#pragma unroll
    for (int i = 0; i < 4; ++i) {
      int cellbase = (wv * 4 + i) * 64;      // wave-uniform LDS base
      int cell = cellbase + lane;
      int r  = cell >> 3;                    // tile row 0..127
      int kb = (cell & 7) ^ (r & 7);         // swizzled k-block
      load16_to_lds(A + (size_t)(m0 + r) * K + kt + kb * 8, &lA[cellbase]);
      load16_to_lds(B + (size_t)(n0 + r) * K + kt + kb * 8, &lB[cellbase]);
    }
    __syncthreads();
#pragma unroll
    for (int ks = 0; ks < 2; ++ks) {
      bf16x8 af[4], bfr[4];
      const int kb = ks * 4 + grp;
#pragma unroll
      for (int f = 0; f < 4; ++f) {
        int m = wm + f * 16 + mk;
        af[f]  = *(const bf16x8*)&lA[m * 8 + (kb ^ (m & 7))];
        int n = wn + f * 16 + mk;
        bfr[f] = *(const bf16x8*)&lB[n * 8 + (kb ^ (n & 7))];
      }
#pragma unroll
      for (int i = 0; i < 4; ++i)
#pragma unroll
        for (int j = 0; j < 4; ++j)
          acc[i][j] = __builtin_amdgcn_mfma_f32_16x16x32_bf16(af[i], bfr[j], acc[i][j], 0, 0, 0);
    }
    __syncthreads();
  }

  // Epilogue. C/D mapping (m89-verified): col = lane&15, row = (lane>>4)*4 + reg.
#pragma unroll
  for (int i = 0; i < 4; ++i)
#pragma unroll
    for (int j = 0; j < 4; ++j) {
      int row = m0 + wm + i * 16 + grp * 4;
      int col = n0 + wn + j * 16 + mk;
#pragma unroll
      for (int r = 0; r < 4; ++r)
        C[(size_t)(row + r) * N + col] = __float2bfloat16(acc[i][j][r]);
    }
}

// ---------------------------------------------------------------------------
// Per-neuron LIF scan for layer 1. Thread = (b, h). t-unrolled x4 with
// batched loads (4 independent loads issued before the dependent updates).
// ---------------------------------------------------------------------------
__global__ __launch_bounds__(256) void scan1_kernel(
    const __hip_bfloat16* __restrict__ cur1, const float* __restrict__ b1,
    const float* __restrict__ wt1, unsigned long long* __restrict__ mask1,
    int h_off, int Nc) {
  const int hl = threadIdx.x + blockIdx.x * 256;     // within chunk
  const int b  = blockIdx.y;
  const int hg = h_off + hl;                         // global h1
  const int lane = threadIdx.x & 63;
  const float bias = b1[hg];
  const float k    = lif_k(wt1[hg]);
  const int mword = hg >> 6;
  float v = 0.0f;
  for (int t = 0; t < T_STEPS; t += 4) {
    float c[4];
#pragma unroll
    for (int u = 0; u < 4; ++u)
      c[u] = __bfloat162float(cur1[(size_t)((t + u) * BATCH + b) * Nc + hl]);
#pragma unroll
    for (int u = 0; u < 4; ++u) {
      v = fmaf(k, (c[u] + bias) - v, v);
      bool sp = v > 1.0f;
      unsigned long long bm = __ballot(sp);
      if (lane == 0) mask1[(size_t)((t + u) * BATCH + b) * (H1_F / 64) + mword] = bm;
      if (sp) v = 0.0f;
    }
  }
}

// ---------------------------------------------------------------------------
// Fused layers 2+3. One block per batch element b; 1024 threads (16 waves).
// Each thread owns h2 = {tid, tid+1024}; threads 0..511 also own out-neuron tid.
// mask2 lives in LDS (never global). mask1 row prefetched one t ahead.
// Event-driven currents: exact for any input, ~zero work when no spikes.
// ---------------------------------------------------------------------------
__global__ __launch_bounds__(1024) void layer23_kernel(
    const unsigned long long* __restrict__ mask1,
    const float* __restrict__ W2, const float* __restrict__ b2, const float* __restrict__ wt2,
    const float* __restrict__ W3, const float* __restrict__ b3, const float* __restrict__ wt3,
    float* __restrict__ out_s, float* __restrict__ out_v) {
  __shared__ unsigned long long m2sh[32];
  const int tid = threadIdx.x, b = blockIdx.x;
  const int lane = tid & 63, wv = tid >> 6;

  const float bias2a = b2[tid], bias2b = b2[tid + 1024];
  const float k2a = lif_k(wt2[tid]), k2b = lif_k(wt2[tid + 1024]);
  const float* W2a = W2 + (size_t)tid * H1_F;
  const float* W2b = W2 + (size_t)(tid + 1024) * H1_F;
  float v2a = 0.0f, v2b = 0.0f;

  float bias3 = 0.0f, k3 = 0.0f, v3 = 0.0f;
  const float* W3r = W3;
  if (wv < 8) {  // threads 0..511
    bias3 = b3[tid];
    k3 = lif_k(wt3[tid]);
    W3r = W3 + (size_t)tid * H2_F;
  }

  unsigned long long nxt =
      (lane < 32) ? mask1[(size_t)(0 * BATCH + b) * 32 + lane] : 0ull;

  for (int t = 0; t < T_STEPS; ++t) {
    unsigned long long wrd = nxt;
    if (t + 1 < T_STEPS)
      nxt = (lane < 32) ? mask1[(size_t)((t + 1) * BATCH + b) * 32 + lane] : 0ull;

    // ---- layer 2: two neurons per thread, event-driven current ----
    float cura = bias2a, curb = bias2b;
    if (__ballot(wrd != 0ull)) {
      for (int wi = 0; wi < 32; ++wi) {
        unsigned long long m = __shfl(wrd, wi, 64);
        while (m) {
          int bit = __ffsll(m) - 1;
          m &= m - 1;
          int idx = wi * 64 + bit;
          cura += W2a[idx];
          curb += W2b[idx];
        }
      }
    }
    v2a = fmaf(k2a, cura - v2a, v2a);
    v2b = fmaf(k2b, curb - v2b, v2b);
    bool spa = v2a > 1.0f, spb = v2b > 1.0f;
    unsigned long long ba = __ballot(spa);
    unsigned long long bb = __ballot(spb);
    if (lane == 0) { m2sh[wv] = ba; m2sh[16 + wv] = bb; }
    if (spa) v2a = 0.0f;
    if (spb) v2b = 0.0f;
    __syncthreads();

    // ---- layer 3: waves 0..7 (threads 0..511) ----
    if (wv < 8) {
      unsigned long long w3m = (lane < 32) ? m2sh[lane] : 0ull;
      float cur3 = bias3;
      if (__ballot(w3m != 0ull)) {
        for (int wi = 0; wi < 32; ++wi) {
          unsigned long long m = __shfl(w3m, wi, 64);
          while (m) {
            int bit = __ffsll(m) - 1;
            m &= m - 1;
            cur3 += W3r[wi * 64 + bit];
          }
        }
      }
      float vp = fmaf(k3, cur3 - v3, v3);   // pre-reset membrane (v_tmp)
      bool sp = vp > 1.0f;
      size_t idx = (size_t)(t * BATCH + b) * OUT_F + tid;
      out_s[idx] = sp ? 1.0f : 0.0f;
      out_v[idx] = vp;
      v3 = sp ? 0.0f : vp;
    }
    __syncthreads();
  }
}

// ---------------------------------------------------------------------------
extern "C" void kernel_launch(void* const* d_in, const int* in_sizes, int n_in,
                              void* d_out, int out_size, void* d_ws, size_t ws_size,
                              hipStream_t stream) {
  const float* s   = (const float*)d_in[0];
  const float* W1  = (const float*)d_in[1];
  const float* b1  = (const float*)d_in[2];
  const float* wt1 = (const float*)d_in[3];
  const float* W2  = (const float*)d_in[4];
  const float* b2  = (const float*)d_in[5];
  const float* wt2 = (const float*)d_in[6];
  const float* W3  = (const float*)d_in[7];
  const float* b3  = (const float*)d_in[8];
  const float* wt3 = (const float*)d_in[9];

  // Workspace layout: [mask1 8MB][s_bf16 67MB][W1_bf16 4MB][cur1 chunk]
  char* wsb = (char*)d_ws;
  const size_t MASK_BYTES = (size_t)T_STEPS * BATCH * (H1_F / 64) * 8;  // 8.4 MB
  const size_t S_ELEMS  = (size_t)M_TOT * IN_F;     // 33.55M
  const size_t W1_ELEMS = (size_t)H1_F * IN_F;      // 2.10M
  unsigned long long* mask1 = (unsigned long long*)wsb;
  __hip_bfloat16* s_bf  = (__hip_bfloat16*)(wsb + MASK_BYTES);
  __hip_bfloat16* W1_bf = s_bf + S_ELEMS;
  __hip_bfloat16* cur1  = W1_bf + W1_ELEMS;
  const size_t fixed = MASK_BYTES + (S_ELEMS + W1_ELEMS) * sizeof(__hip_bfloat16);

  // Adaptive H1 chunking: fewest chunks whose cur1 buffer fits remaining ws.
  const size_t avail = ws_size > fixed ? ws_size - fixed : 0;
  int nc = 8;
  for (int c = 1; c <= 8; c *= 2) {
    if ((size_t)M_TOT * (H1_F / c) * sizeof(__hip_bfloat16) <= avail) { nc = c; break; }
  }
  const int Nc = H1_F / nc;   // >= 256

  float* outs = (float*)d_out;
  float* outv = outs + (size_t)T_STEPS * BATCH * OUT_F;

  const int s4 = (int)(S_ELEMS / 4), w4 = (int)(W1_ELEMS / 4);
  cvt_both<<<(s4 + w4 + 255) / 256, 256, 0, stream>>>(
      (const float4*)s, (ushort4*)s_bf, s4, (const float4*)W1, (ushort4*)W1_bf, w4);

  for (int c = 0; c < nc; ++c) {
    gemm_bt<<<(M_TOT / 128) * (Nc / 128), 256, 0, stream>>>(
        s_bf, W1_bf + (size_t)c * Nc * IN_F, cur1, Nc);
    scan1_kernel<<<dim3(Nc / 256, BATCH), 256, 0, stream>>>(
        cur1, b1, wt1, mask1, c * Nc, Nc);
  }
  layer23_kernel<<<BATCH, 1024, 0, stream>>>(mask1, W2, b2, wt2, W3, b3, wt3, outs, outv);
}